// Round 6
// baseline (524.415 us; speedup 1.0000x reference)
//
#include <hip/hip_runtime.h>
#include <hip/hip_bf16.h>
#include <math.h>

#define BB 64
#define IN_CH 256
#define CH 128
#define OUT_CH 256
#define SP 256        // RES*RES
#define EMBED 64
#define N_EMBED 1024
#define NPH 64
#define FLAT_IN 16384
#define FLAT_Z 4096

typedef short bf16x8 __attribute__((ext_vector_type(8)));
typedef float f32x4 __attribute__((ext_vector_type(4)));

__device__ __forceinline__ float silu_f(float x){ return x / (1.0f + expf(-x)); }

__device__ __forceinline__ void gl_lds16(const void* g, void* l){
  __builtin_amdgcn_global_load_lds(
      (const __attribute__((address_space(1))) void*)g,
      (__attribute__((address_space(3))) void*)l, 16, 0, 0);
}

// ---- fused conv_in(1x1)+silu + LN stats(fp64) + LN apply + bf16
// block=(b,half): h[b][half*64..+64][256p] in regs -> Ahi[ws*64+b][16384] bf16
__global__ __launch_bounds__(256) void k_fused_in(const float* __restrict__ x,
    const float* __restrict__ w1, const float* __restrict__ b1,
    const float* __restrict__ gp, const float* __restrict__ bp,
    const float* __restrict__ gn, const float* __restrict__ bnl,
    __hip_bfloat16* __restrict__ Ahi)
{
  int b = blockIdx.x, ws = blockIdx.y;
  int t = threadIdx.x;            // = spatial p
  int d0 = ws*64;
  float acc[64];
  #pragma unroll
  for (int j=0;j<64;j++) acc[j] = b1[d0+j];
  const float* xb = x + (size_t)b*IN_CH*SP + t;
  for (int c=0;c<IN_CH;c++){
    float xv = xb[(size_t)c*SP];
    #pragma unroll
    for (int j=0;j<64;j++) acc[j] = fmaf(xv, w1[c*CH + d0 + j], acc[j]);
  }
  double s1=0.0, s2=0.0;
  #pragma unroll
  for (int j=0;j<64;j++){
    float v = silu_f(acc[j]);
    acc[j] = v;
    double dv = (double)v;
    s1 += dv; s2 += dv*dv;
  }
  __shared__ double l1[256], l2[256];
  l1[t]=s1; l2[t]=s2; __syncthreads();
  for (int s=128; s>0; s>>=1){
    if (t<s){ l1[t]+=l1[t+s]; l2[t]+=l2[t+s]; }
    __syncthreads();
  }
  double m = l1[0]/(double)FLAT_IN;
  double v = l2[0]/(double)FLAT_IN - m*m;
  float mf = (float)m;
  float rs = (float)(1.0/sqrt(v+1e-5));
  const float* g  = ws? gn : gp;
  const float* bb = ws? bnl: bp;
  __hip_bfloat16* oh = Ahi + ((size_t)ws*64 + b)*FLAT_IN;
  #pragma unroll 4
  for (int j=0;j<64;j++){
    int k = j*256 + t;
    float val = fmaf((acc[j]-mf)*rs, g[k], bb[k]);
    oh[k] = __float2bfloat16(val);
  }
}

// ---- per-wave-pipelined bf16 MFMA split-K GEMM, M=64.
// 4 independent waves per block, ZERO intra-loop barriers. Each wave:
// private double-buffered 4KB W LDS tile (32k x 32n), A-frags global->reg ping-pong,
// counted s_waitcnt vmcnt(8) per step (8 VMEM per stage: 4 gl_lds + 4 A loads).
// part[(wsel*KC+kc)*64 + m][N]
template<int N, int K>
__global__ __launch_bounds__(256) void k_gemm_mfma(
    const __hip_bfloat16* __restrict__ A,
    const float* __restrict__ W0, const float* __restrict__ W1,
    float* __restrict__ part, int CHUNK, int KC)
{
  __shared__ float wlds[4*2048];   // per wave: 2 buffers x 1024 floats (32k x 32n)
  int nt = blockIdx.x, kc = blockIdx.y, wsel = blockIdx.z;
  const float* W = wsel ? W1 : W0;
  int t = threadIdx.x;
  int wave = t >> 6, lane = t & 63;
  int rl = lane & 15;
  int g  = lane >> 4;              // 0..3 (k-group)
  int nbase = nt*128 + wave*32;
  int k0 = kc*CHUNK;

  const __hip_bfloat16* Aw = A + (size_t)wsel*64*K;
  float* wbuf = &wlds[wave*2048];

  // stage source offsets (floats), i=0..3: row = i*8 + (lane>>3),
  // col granule = (lane&7)*4, pre-swizzled by ^((i&1)<<4); dest linear.
  int src_off[4];
  #pragma unroll
  for (int i=0;i<4;i++)
    src_off[i] = (i*8 + (lane>>3))*N + nbase + ((((lane&7)*4)) ^ ((i&1)<<4));

  // read-side bases (floats within buffer): row kg=g*8, col (f*16+rl)^((g&1)<<4)
  int rb0 = g*8*32 + ((rl)      ^ ((g&1)<<4));
  int rb1 = g*8*32 + ((16 + rl) ^ ((g&1)<<4));

  f32x4 acc[4][2];
  #pragma unroll
  for (int mf=0; mf<4; ++mf){ acc[mf][0] = (f32x4){0,0,0,0}; acc[mf][1] = (f32x4){0,0,0,0}; }

  bf16x8 aA[4], aB[4];

  auto STAGE = [&](int buf, int ks, bf16x8 (&areg)[4]){
    const float* Wr = W + (size_t)(k0 + ks*32)*N;
    float* dst = wbuf + buf*1024;
    #pragma unroll
    for (int i=0;i<4;i++) gl_lds16(Wr + src_off[i], dst + i*256);
    size_t ko = (size_t)k0 + (size_t)ks*32 + g*8;
    #pragma unroll
    for (int mf=0; mf<4; ++mf)
      areg[mf] = *(const bf16x8*)(Aw + (size_t)(mf*16+rl)*K + ko);
  };

  auto COMPUTE = [&](int buf, bf16x8 (&areg)[4]){
    const float* lb = wbuf + buf*1024;
    float wv0[8], wv1[8];
    #pragma unroll
    for (int j=0;j<8;j++){ wv0[j] = lb[rb0 + j*32]; wv1[j] = lb[rb1 + j*32]; }
    bf16x8 bh0, bh1;
    #pragma unroll
    for (int j=0;j<8;j++){
      bh0[j] = __builtin_bit_cast(short, __float2bfloat16(wv0[j]));
      bh1[j] = __builtin_bit_cast(short, __float2bfloat16(wv1[j]));
    }
    #pragma unroll
    for (int mf=0; mf<4; ++mf){
      acc[mf][0] = __builtin_amdgcn_mfma_f32_16x16x32_bf16(areg[mf], bh0, acc[mf][0], 0,0,0);
      acc[mf][1] = __builtin_amdgcn_mfma_f32_16x16x32_bf16(areg[mf], bh1, acc[mf][1], 0,0,0);
    }
  };

  int NT_ = CHUNK/32;              // always even (>=32)
  STAGE(0, 0, aA);
  for (int ks2=0; ks2<NT_/2; ++ks2){
    // even step 2*ks2: uses buf0/aA; prefetch step 2*ks2+1 into buf1/aB
    STAGE(1, 2*ks2+1, aB);
    __builtin_amdgcn_sched_barrier(0);
    asm volatile("s_waitcnt vmcnt(8)" ::: "memory");
    __builtin_amdgcn_sched_barrier(0);
    COMPUTE(0, aA);
    // odd step 2*ks2+1: uses buf1/aB; prefetch step 2*ks2+2 into buf0/aA
    int ksn = (2*ks2+2 < NT_) ? 2*ks2+2 : 2*ks2+1;   // tail: dummy restage (never read)
    STAGE(0, ksn, aA);
    __builtin_amdgcn_sched_barrier(0);
    asm volatile("s_waitcnt vmcnt(8)" ::: "memory");
    __builtin_amdgcn_sched_barrier(0);
    COMPUTE(1, aB);
  }
  asm volatile("s_waitcnt vmcnt(0)" ::: "memory");  // drain trailing stage

  float* P = part + ((size_t)((wsel*KC + kc)*64))*N + nbase + rl;
  #pragma unroll
  for (int mf=0; mf<4; ++mf)
    #pragma unroll
    for (int f=0; f<2; ++f)
      #pragma unroll
      for (int r=0; r<4; ++r)
        P[((size_t)(mf*16 + g*4 + r))*N + f*16] = acc[mf][f][r];
}

// ---- z = sum partials + bias; z[ws][m][4096]
__global__ __launch_bounds__(256) void k_zreduce(const float* __restrict__ part,
  const float* __restrict__ bp, const float* __restrict__ bn,
  float* __restrict__ z, int KC)
{
  int idx = blockIdx.x*256 + threadIdx.x;     // < 2*64*4096
  int ws = idx >> 18; int rem = idx & 262143;
  int m = rem >> 12; int n = rem & 4095;
  float s = (ws? bn: bp)[n];
  const float* p = part + ((size_t)ws*KC*64 + m)*4096 + n;
  for (int kc=0;kc<KC;kc++) s += p[(size_t)kc*64*4096];
  z[idx] = s;
}

// ---- codebook squared norms
__global__ __launch_bounds__(256) void k_cc(const float* __restrict__ cb, float* __restrict__ cc){
  int j = blockIdx.x*256 + threadIdx.x;
  if (j >= N_EMBED) return;
  float s=0.f;
  for (int e=0;e<EMBED;e++){ float c = cb[(size_t)j*EMBED+e]; s = fmaf(c,c,s); }
  cc[j]=s;
}

// ---- argmin scan over a 64-code split; score s = cc[j] - 2*z.c[j]
__global__ __launch_bounds__(256) void k_qscan(const float* __restrict__ z,
  const float* __restrict__ cb, const float* __restrict__ cc,
  float* __restrict__ bests, int* __restrict__ bestj)
{
  int r = blockIdx.x*256 + threadIdx.x;   // < 8192
  int cs = blockIdx.y;                    // 16 splits of 64 codes
  int ws = r>>12, rem = r&4095; int b = rem>>6, rr = rem&63;
  const float* zr = z + (size_t)ws*BB*FLAT_Z + (size_t)b*FLAT_Z + rr;
  float zr_[EMBED];
  #pragma unroll
  for (int e=0;e<EMBED;e++) zr_[e] = zr[(size_t)e*64];
  float best = 3.4e38f; int bj = 0;
  int j0 = cs*64;
  for (int jj=0;jj<64;jj++){
    int j = j0 + jj;
    const float* c = cb + (size_t)j*EMBED;
    float s1 = 0.f;
    #pragma unroll
    for (int e=0;e<EMBED;e++) s1 = fmaf(c[e], zr_[e], s1);
    float s = fmaf(-2.f, s1, cc[j]);
    if (s < best){ best = s; bj = j; }   // strict < : first-index semantics
  }
  bests[(size_t)cs*8192 + r] = best;
  bestj[(size_t)cs*8192 + r] = bj;
}

// ---- finalize: combine splits, write zqA bf16 [ws*64+b][4096], row sse
__global__ __launch_bounds__(256) void k_qfin(const float* __restrict__ z,
  const float* __restrict__ cb, const float* __restrict__ bests, const int* __restrict__ bestj,
  __hip_bfloat16* __restrict__ zqA, float* __restrict__ row_sse)
{
  int r = blockIdx.x*256 + threadIdx.x;
  float best = 3.4e38f; int bj = 0;
  for (int cs=0;cs<16;cs++){              // ascending code ranges
    float v = bests[(size_t)cs*8192 + r];
    int j = bestj[(size_t)cs*8192 + r];
    if (v < best){ best=v; bj=j; }
  }
  int ws = r>>12, rem = r&4095; int b = rem>>6, rr = rem&63;
  const float* zr = z + (size_t)ws*BB*FLAT_Z + (size_t)b*FLAT_Z + rr;
  const float* c = cb + (size_t)bj*EMBED;
  __hip_bfloat16* zq = zqA + ((size_t)ws*64 + b)*FLAT_Z;
  float sse = 0.f;
  #pragma unroll
  for (int e=0;e<EMBED;e++){
    float cv = c[e];
    float zv = zr[(size_t)e*64];
    float d = cv - zv; sse = fmaf(d,d,sse);
    zq[(size_t)e*64 + rr] = __float2bfloat16(cv);
  }
  row_sse[r] = sse;
}

// ---- loss reduce (deterministic, fp64)
__global__ __launch_bounds__(256) void k_loss(const float* __restrict__ row_sse, float* __restrict__ out){
  __shared__ double l[256];
  double s=0.0;
  for (int i=threadIdx.x;i<8192;i+=256) s += (double)row_sse[i];
  l[threadIdx.x]=s; __syncthreads();
  for (int st=128;st>0;st>>=1){ if (threadIdx.x<st) l[threadIdx.x]+=l[threadIdx.x+st]; __syncthreads(); }
  if (threadIdx.x==0) out[(size_t)BB*OUT_CH*SP] = (float)(l[0]*1.25/262144.0);
}

// ---- hout reduce + bias -> h_[m][128][256]
__global__ __launch_bounds__(256) void k_hreduce(const float* __restrict__ part,
  const float* __restrict__ bp, const float* __restrict__ bn,
  float* __restrict__ hbuf, int KC)
{
  int idx = blockIdx.x*256 + threadIdx.x;  // < 2*64*16384
  int ws = idx >> 20; int rem = idx & 1048575;
  int m = rem >> 14; int n = rem & 16383;
  float s = (ws? bn: bp)[n];
  const float* p = part + ((size_t)ws*KC*64 + m)*16384 + n;
  for (int kc=0;kc<KC;kc++) s += p[(size_t)kc*64*16384];
  hbuf[((size_t)m*CH + ws*NPH + (n>>8))*SP + (n&255)] = s;
}

// ---- conv_out (silu on input) -> d_out; dg<4, 64 d each
__global__ __launch_bounds__(256) void k_conv_out(const float* __restrict__ hbuf,
  const float* __restrict__ w2, const float* __restrict__ b2, float* __restrict__ out)
{
  int b = blockIdx.x, dg = blockIdx.y;
  int p = threadIdx.x;
  int d0 = dg*64;
  float acc[64];
  #pragma unroll
  for (int j=0;j<64;j++) acc[j]=b2[d0+j];
  const float* hb = hbuf + (size_t)b*CH*SP + p;
  for (int c=0;c<CH;c++){
    float hv = silu_f(hb[(size_t)c*SP]);
    #pragma unroll
    for (int j=0;j<64;j++) acc[j] = fmaf(hv, w2[c*OUT_CH + d0 + j], acc[j]);
  }
  float* ob = out + (size_t)b*OUT_CH*SP + (size_t)d0*SP + p;
  #pragma unroll
  for (int j=0;j<64;j++) ob[(size_t)j*SP] = acc[j];
}

extern "C" void kernel_launch(void* const* d_in, const int* in_sizes, int n_in,
                              void* d_out, int out_size, void* d_ws, size_t ws_size,
                              hipStream_t stream)
{
  const float* x   = (const float*)d_in[0];
  const float* w1  = (const float*)d_in[1];
  const float* b1  = (const float*)d_in[2];
  const float* gp  = (const float*)d_in[3];
  const float* bp  = (const float*)d_in[4];
  const float* Wip = (const float*)d_in[5];
  const float* bip = (const float*)d_in[6];
  const float* gn  = (const float*)d_in[7];
  const float* bnl = (const float*)d_in[8];
  const float* Win = (const float*)d_in[9];
  const float* bin = (const float*)d_in[10];
  const float* cb  = (const float*)d_in[11];
  const float* Wop = (const float*)d_in[12];
  const float* bop = (const float*)d_in[13];
  const float* Won = (const float*)d_in[14];
  const float* bon = (const float*)d_in[15];
  const float* w2  = (const float*)d_in[16];
  const float* b2  = (const float*)d_in[17];
  float* out = (float*)d_out;
  float* ws  = (float*)d_ws;

  __hip_bfloat16* Ahi = (__hip_bfloat16*)ws;               // 1,048,576 f
  float* z    = ws + 1048576;                              // 524,288 f
  __hip_bfloat16* zqA = (__hip_bfloat16*)(ws + 1572864);   // 262,144 f
  float* hh   = ws + 1835008;                              // 2,097,152 f
  float* cc   = ws + 3932160;                              // 1,024 f
  float* sse  = ws + 3933184;                              // 8,192 f
  float* bests= ws + 3941376;                              // 131,072 f
  int*   bestj= (int*)(ws + 4072448);                      // 131,072
  float* part = ws + 4203520;                              // up to 8,388,608 f

  size_t wsf = ws_size/4;
  int KCe=16, KCd=4;
  if (wsf < (size_t)4203520 + 8388608) { KCe=8; KCd=2; }
  if (wsf < (size_t)4203520 + 4194304) { KCe=4; KCd=1; }

  k_fused_in<<<dim3(64,2),256,0,stream>>>(x,w1,b1,gp,bp,gn,bnl,Ahi);
  k_gemm_mfma<4096,16384><<<dim3(32,KCe,2),256,0,stream>>>(Ahi,Wip,Win,part,16384/KCe,KCe);
  k_zreduce<<<2048,256,0,stream>>>(part,bip,bin,z,KCe);
  k_cc<<<4,256,0,stream>>>(cb,cc);
  k_qscan<<<dim3(32,16),256,0,stream>>>(z,cb,cc,bests,bestj);
  k_qfin<<<32,256,0,stream>>>(z,cb,bests,bestj,zqA,sse);
  k_gemm_mfma<16384,4096><<<dim3(128,KCd,2),256,0,stream>>>(zqA,Wop,Won,part,4096/KCd,KCd);
  k_hreduce<<<8192,256,0,stream>>>(part,bop,bon,hh,KCd);
  k_conv_out<<<dim3(64,4),256,0,stream>>>(hh,w2,b2,out);
  k_loss<<<1,256,0,stream>>>(sse,out);
}

// Round 7
// 451.309 us; speedup vs baseline: 1.1620x; 1.1620x over previous
//
#include <hip/hip_runtime.h>
#include <hip/hip_bf16.h>
#include <math.h>

#define BB 64
#define IN_CH 256
#define CH 128
#define OUT_CH 256
#define SP 256        // RES*RES
#define EMBED 64
#define N_EMBED 1024
#define NPH 64
#define FLAT_IN 16384
#define FLAT_Z 4096

typedef short bf16x8 __attribute__((ext_vector_type(8)));
typedef float f32x4 __attribute__((ext_vector_type(4)));

__device__ __forceinline__ float silu_f(float x){ return x / (1.0f + expf(-x)); }

__device__ __forceinline__ void gl_lds16(const void* g, void* l){
  __builtin_amdgcn_global_load_lds(
      (const __attribute__((address_space(1))) void*)g,
      (__attribute__((address_space(3))) void*)l, 16, 0, 0);
}

// ---- fused conv_in(1x1)+silu + LN stats(fp64) + LN apply + bf16
// block=(b,half): h[b][half*64..+64][256p] in regs -> Ahi[ws*64+b][16384] bf16
__global__ __launch_bounds__(256) void k_fused_in(const float* __restrict__ x,
    const float* __restrict__ w1, const float* __restrict__ b1,
    const float* __restrict__ gp, const float* __restrict__ bp,
    const float* __restrict__ gn, const float* __restrict__ bnl,
    __hip_bfloat16* __restrict__ Ahi)
{
  int b = blockIdx.x, ws = blockIdx.y;
  int t = threadIdx.x;            // = spatial p
  int d0 = ws*64;
  float acc[64];
  #pragma unroll
  for (int j=0;j<64;j++) acc[j] = b1[d0+j];
  const float* xb = x + (size_t)b*IN_CH*SP + t;
  for (int c=0;c<IN_CH;c++){
    float xv = xb[(size_t)c*SP];
    #pragma unroll
    for (int j=0;j<64;j++) acc[j] = fmaf(xv, w1[c*CH + d0 + j], acc[j]);
  }
  double s1=0.0, s2=0.0;
  #pragma unroll
  for (int j=0;j<64;j++){
    float v = silu_f(acc[j]);
    acc[j] = v;
    double dv = (double)v;
    s1 += dv; s2 += dv*dv;
  }
  __shared__ double l1[256], l2[256];
  l1[t]=s1; l2[t]=s2; __syncthreads();
  for (int s=128; s>0; s>>=1){
    if (t<s){ l1[t]+=l1[t+s]; l2[t]+=l2[t+s]; }
    __syncthreads();
  }
  double m = l1[0]/(double)FLAT_IN;
  double v = l2[0]/(double)FLAT_IN - m*m;
  float mf = (float)m;
  float rs = (float)(1.0/sqrt(v+1e-5));
  const float* g  = ws? gn : gp;
  const float* bb = ws? bnl: bp;
  __hip_bfloat16* oh = Ahi + ((size_t)ws*64 + b)*FLAT_IN;
  #pragma unroll 4
  for (int j=0;j<64;j++){
    int k = j*256 + t;
    float val = fmaf((acc[j]-mf)*rs, g[k], bb[k]);
    oh[k] = __float2bfloat16(val);
  }
}

// ---- streaming bf16 MFMA split-K GEMM, M=64, depth-2 pipeline (3 LDS buffers).
// Block-level staging (round-5 layout), 5 gl_lds per stage (4 W + 1 A).
// Per step: vmcnt(5) [stage k done, k+1 in flight] -> s_barrier -> STAGE(k+2) -> compute k.
// part[(wsel*KC+kc)*64 + m][N]
template<int N, int K>
__global__ __launch_bounds__(256) void k_gemm_mfma(
    const __hip_bfloat16* __restrict__ A,
    const float* __restrict__ W0, const float* __restrict__ W1,
    float* __restrict__ part, int CHUNK, int KC)
{
  __shared__ float wlds[3*4096];   // 3 x (32k x 128n) fp32 = 48KB
  __shared__ float alds[3*1024];   // 3 x (64m x 32k) bf16 = 12KB
  int nt = blockIdx.x, kc = blockIdx.y, wsel = blockIdx.z;
  const float* W = wsel ? W1 : W0;
  int t = threadIdx.x;
  int wave = t >> 6, lane = t & 63;
  int rl = lane & 15;
  int g  = lane >> 4;              // 0..3 (k-group)
  int kg = g * 8;
  int nbase = nt*128;
  int k0 = kc*CHUNK;

  const __hip_bfloat16* Aw = A + (size_t)wsel*64*K;

  // W LDS swizzle: s(kl) = ((kl>>3)&1)<<4 | ((kl>>3)&2)<<1
  int s_lane = ((g&1)<<4) | ((g&2)<<1);
  int wbase0 = kg*128 + ((wave*32 + rl) ^ s_lane);
  int wbase1 = kg*128 + ((wave*32 + 16 + rl) ^ s_lane);
  // A read byte offset within buffer: row m=mf*16+rl (64B), col16 = g ^ ((rl>>1)&3)
  int abyte[4];
  #pragma unroll
  for (int mf=0; mf<4; ++mf)
    abyte[mf] = (mf*16+rl)*64 + ((g ^ ((rl>>1)&3))<<4);

  // W stage: dest linear, source col pre-swizzled
  int src_off[4]; int dst_base[4];
  #pragma unroll
  for (int i=0;i<4;i++){
    int fi = (i*4+wave)*256 + lane*4;
    int kl = fi>>7, nn = fi&127;
    int s = (((kl>>3)&1)<<4) | (((kl>>3)&2)<<1);
    src_off[i] = kl*N + nbase + (nn ^ s);
    dst_base[i] = (i*4+wave)*256;           // wave-uniform
  }
  // A stage: thread t writes LDS bytes t*16 (m=t>>2, granule t&3); source k-quad swizzled
  size_t a_src = (size_t)(t>>2)*K + (size_t)(((t&3)^((t>>3)&3))*8);
  int a_dst = wave*256;                     // floats, wave-uniform

  f32x4 acc[4][2];
  #pragma unroll
  for (int mf=0; mf<4; ++mf){ acc[mf][0] = (f32x4){0,0,0,0}; acc[mf][1] = (f32x4){0,0,0,0}; }

  auto STAGE = [&](int buf, int ks){
    const float* Wr = W + (size_t)(k0 + ks*32)*N;
    float* lb = &wlds[buf*4096];
    #pragma unroll
    for (int i=0;i<4;i++) gl_lds16(Wr + src_off[i], lb + dst_base[i]);
    gl_lds16(Aw + a_src + (size_t)(k0 + ks*32), &alds[buf*1024] + a_dst);
  };

  int NT_ = CHUNK/32;
  STAGE(0, 0);
  STAGE(1, 1);

  for (int ks=0; ks<NT_; ++ks){
    int cur = ks % 3;
    __builtin_amdgcn_sched_barrier(0);
    if (ks < NT_-1) { asm volatile("s_waitcnt vmcnt(5)" ::: "memory"); }
    else            { asm volatile("s_waitcnt vmcnt(0)" ::: "memory"); }
    __builtin_amdgcn_sched_barrier(0);
    __builtin_amdgcn_s_barrier();            // all waves: stage ks ready, prev reads done
    __builtin_amdgcn_sched_barrier(0);
    if (ks+2 < NT_) STAGE((ks+2)%3, ks+2);   // overwrites buf (ks-1)%3: consumed by all waves
    __builtin_amdgcn_sched_barrier(0);

    const float* lb = &wlds[cur*4096];
    const char* ab = (const char*)&alds[cur*1024];
    bf16x8 ah[4];
    #pragma unroll
    for (int mf=0; mf<4; ++mf) ah[mf] = *(const bf16x8*)(ab + abyte[mf]);
    float wv0[8], wv1[8];
    #pragma unroll
    for (int j=0;j<8;j++){ wv0[j] = lb[wbase0 + j*128]; wv1[j] = lb[wbase1 + j*128]; }
    bf16x8 bh0, bh1;
    #pragma unroll
    for (int j=0;j<8;j++){
      bh0[j] = __builtin_bit_cast(short, __float2bfloat16(wv0[j]));
      bh1[j] = __builtin_bit_cast(short, __float2bfloat16(wv1[j]));
    }
    #pragma unroll
    for (int mf=0; mf<4; ++mf){
      acc[mf][0] = __builtin_amdgcn_mfma_f32_16x16x32_bf16(ah[mf], bh0, acc[mf][0], 0,0,0);
      acc[mf][1] = __builtin_amdgcn_mfma_f32_16x16x32_bf16(ah[mf], bh1, acc[mf][1], 0,0,0);
    }
  }

  float* P = part + ((size_t)((wsel*KC + kc)*64))*N + nbase + wave*32 + rl;
  #pragma unroll
  for (int mf=0; mf<4; ++mf)
    #pragma unroll
    for (int f=0; f<2; ++f)
      #pragma unroll
      for (int r=0; r<4; ++r)
        P[((size_t)(mf*16 + g*4 + r))*N + f*16] = acc[mf][f][r];
}

// ---- z = sum partials + bias; z[ws][m][4096]
__global__ __launch_bounds__(256) void k_zreduce(const float* __restrict__ part,
  const float* __restrict__ bp, const float* __restrict__ bn,
  float* __restrict__ z, int KC)
{
  int idx = blockIdx.x*256 + threadIdx.x;     // < 2*64*4096
  int ws = idx >> 18; int rem = idx & 262143;
  int m = rem >> 12; int n = rem & 4095;
  float s = (ws? bn: bp)[n];
  const float* p = part + ((size_t)ws*KC*64 + m)*4096 + n;
  for (int kc=0;kc<KC;kc++) s += p[(size_t)kc*64*4096];
  z[idx] = s;
}

// ---- codebook squared norms
__global__ __launch_bounds__(256) void k_cc(const float* __restrict__ cb, float* __restrict__ cc){
  int j = blockIdx.x*256 + threadIdx.x;
  if (j >= N_EMBED) return;
  float s=0.f;
  for (int e=0;e<EMBED;e++){ float c = cb[(size_t)j*EMBED+e]; s = fmaf(c,c,s); }
  cc[j]=s;
}

// ---- argmin scan over a 64-code split; score s = cc[j] - 2*z.c[j]
__global__ __launch_bounds__(256) void k_qscan(const float* __restrict__ z,
  const float* __restrict__ cb, const float* __restrict__ cc,
  float* __restrict__ bests, int* __restrict__ bestj)
{
  int r = blockIdx.x*256 + threadIdx.x;   // < 8192
  int cs = blockIdx.y;                    // 16 splits of 64 codes
  int ws = r>>12, rem = r&4095; int b = rem>>6, rr = rem&63;
  const float* zr = z + (size_t)ws*BB*FLAT_Z + (size_t)b*FLAT_Z + rr;
  float zr_[EMBED];
  #pragma unroll
  for (int e=0;e<EMBED;e++) zr_[e] = zr[(size_t)e*64];
  float best = 3.4e38f; int bj = 0;
  int j0 = cs*64;
  for (int jj=0;jj<64;jj++){
    int j = j0 + jj;
    const float* c = cb + (size_t)j*EMBED;
    float s1 = 0.f;
    #pragma unroll
    for (int e=0;e<EMBED;e++) s1 = fmaf(c[e], zr_[e], s1);
    float s = fmaf(-2.f, s1, cc[j]);
    if (s < best){ best = s; bj = j; }   // strict < : first-index semantics
  }
  bests[(size_t)cs*8192 + r] = best;
  bestj[(size_t)cs*8192 + r] = bj;
}

// ---- finalize: combine splits, write zqA bf16 [ws*64+b][4096], row sse
__global__ __launch_bounds__(256) void k_qfin(const float* __restrict__ z,
  const float* __restrict__ cb, const float* __restrict__ bests, const int* __restrict__ bestj,
  __hip_bfloat16* __restrict__ zqA, float* __restrict__ row_sse)
{
  int r = blockIdx.x*256 + threadIdx.x;
  float best = 3.4e38f; int bj = 0;
  for (int cs=0;cs<16;cs++){              // ascending code ranges
    float v = bests[(size_t)cs*8192 + r];
    int j = bestj[(size_t)cs*8192 + r];
    if (v < best){ best=v; bj=j; }
  }
  int ws = r>>12, rem = r&4095; int b = rem>>6, rr = rem&63;
  const float* zr = z + (size_t)ws*BB*FLAT_Z + (size_t)b*FLAT_Z + rr;
  const float* c = cb + (size_t)bj*EMBED;
  __hip_bfloat16* zq = zqA + ((size_t)ws*64 + b)*FLAT_Z;
  float sse = 0.f;
  #pragma unroll
  for (int e=0;e<EMBED;e++){
    float cv = c[e];
    float zv = zr[(size_t)e*64];
    float d = cv - zv; sse = fmaf(d,d,sse);
    zq[(size_t)e*64 + rr] = __float2bfloat16(cv);
  }
  row_sse[r] = sse;
}

// ---- loss reduce (deterministic, fp64)
__global__ __launch_bounds__(256) void k_loss(const float* __restrict__ row_sse, float* __restrict__ out){
  __shared__ double l[256];
  double s=0.0;
  for (int i=threadIdx.x;i<8192;i+=256) s += (double)row_sse[i];
  l[threadIdx.x]=s; __syncthreads();
  for (int st=128;st>0;st>>=1){ if (threadIdx.x<st) l[threadIdx.x]+=l[threadIdx.x+st]; __syncthreads(); }
  if (threadIdx.x==0) out[(size_t)BB*OUT_CH*SP] = (float)(l[0]*1.25/262144.0);
}

// ---- hout reduce + bias -> h_[m][128][256]
__global__ __launch_bounds__(256) void k_hreduce(const float* __restrict__ part,
  const float* __restrict__ bp, const float* __restrict__ bn,
  float* __restrict__ hbuf, int KC)
{
  int idx = blockIdx.x*256 + threadIdx.x;  // < 2*64*16384
  int ws = idx >> 20; int rem = idx & 1048575;
  int m = rem >> 14; int n = rem & 16383;
  float s = (ws? bn: bp)[n];
  const float* p = part + ((size_t)ws*KC*64 + m)*16384 + n;
  for (int kc=0;kc<KC;kc++) s += p[(size_t)kc*64*16384];
  hbuf[((size_t)m*CH + ws*NPH + (n>>8))*SP + (n&255)] = s;
}

// ---- conv_out (silu on input) -> d_out; dg<4, 64 d each
__global__ __launch_bounds__(256) void k_conv_out(const float* __restrict__ hbuf,
  const float* __restrict__ w2, const float* __restrict__ b2, float* __restrict__ out)
{
  int b = blockIdx.x, dg = blockIdx.y;
  int p = threadIdx.x;
  int d0 = dg*64;
  float acc[64];
  #pragma unroll
  for (int j=0;j<64;j++) acc[j]=b2[d0+j];
  const float* hb = hbuf + (size_t)b*CH*SP + p;
  for (int c=0;c<CH;c++){
    float hv = silu_f(hb[(size_t)c*SP]);
    #pragma unroll
    for (int j=0;j<64;j++) acc[j] = fmaf(hv, w2[c*OUT_CH + d0 + j], acc[j]);
  }
  float* ob = out + (size_t)b*OUT_CH*SP + (size_t)d0*SP + p;
  #pragma unroll
  for (int j=0;j<64;j++) ob[(size_t)j*SP] = acc[j];
}

extern "C" void kernel_launch(void* const* d_in, const int* in_sizes, int n_in,
                              void* d_out, int out_size, void* d_ws, size_t ws_size,
                              hipStream_t stream)
{
  const float* x   = (const float*)d_in[0];
  const float* w1  = (const float*)d_in[1];
  const float* b1  = (const float*)d_in[2];
  const float* gp  = (const float*)d_in[3];
  const float* bp  = (const float*)d_in[4];
  const float* Wip = (const float*)d_in[5];
  const float* bip = (const float*)d_in[6];
  const float* gn  = (const float*)d_in[7];
  const float* bnl = (const float*)d_in[8];
  const float* Win = (const float*)d_in[9];
  const float* bin = (const float*)d_in[10];
  const float* cb  = (const float*)d_in[11];
  const float* Wop = (const float*)d_in[12];
  const float* bop = (const float*)d_in[13];
  const float* Won = (const float*)d_in[14];
  const float* bon = (const float*)d_in[15];
  const float* w2  = (const float*)d_in[16];
  const float* b2  = (const float*)d_in[17];
  float* out = (float*)d_out;
  float* ws  = (float*)d_ws;

  __hip_bfloat16* Ahi = (__hip_bfloat16*)ws;               // 1,048,576 f
  float* z    = ws + 1048576;                              // 524,288 f
  __hip_bfloat16* zqA = (__hip_bfloat16*)(ws + 1572864);   // 262,144 f
  float* hh   = ws + 1835008;                              // 2,097,152 f
  float* cc   = ws + 3932160;                              // 1,024 f
  float* sse  = ws + 3933184;                              // 8,192 f
  float* bests= ws + 3941376;                              // 131,072 f
  int*   bestj= (int*)(ws + 4072448);                      // 131,072
  float* part = ws + 4203520;                              // 4,194,304 f

  size_t wsf = ws_size/4;
  int KCe=8, KCd=2;                                        // 512-block grids (2 blocks/CU)
  if (wsf < (size_t)4203520 + 4194304) { KCe=4; KCd=1; }

  k_fused_in<<<dim3(64,2),256,0,stream>>>(x,w1,b1,gp,bp,gn,bnl,Ahi);
  k_gemm_mfma<4096,16384><<<dim3(32,KCe,2),256,0,stream>>>(Ahi,Wip,Win,part,16384/KCe,KCe);
  k_zreduce<<<2048,256,0,stream>>>(part,bip,bin,z,KCe);
  k_cc<<<4,256,0,stream>>>(cb,cc);
  k_qscan<<<dim3(32,16),256,0,stream>>>(z,cb,cc,bests,bestj);
  k_qfin<<<32,256,0,stream>>>(z,cb,bests,bestj,zqA,sse);
  k_gemm_mfma<16384,4096><<<dim3(128,KCd,2),256,0,stream>>>(zqA,Wop,Won,part,4096/KCd,KCd);
  k_hreduce<<<8192,256,0,stream>>>(part,bop,bon,hh,KCd);
  k_conv_out<<<dim3(64,4),256,0,stream>>>(hh,w2,b2,out);
  k_loss<<<1,256,0,stream>>>(sse,out);
}

// Round 8
// 443.180 us; speedup vs baseline: 1.1833x; 1.0183x over previous
//
#include <hip/hip_runtime.h>
#include <hip/hip_bf16.h>
#include <math.h>

#define BB 64
#define IN_CH 256
#define CH 128
#define OUT_CH 256
#define SP 256        // RES*RES
#define EMBED 64
#define N_EMBED 1024
#define NPH 64
#define FLAT_IN 16384
#define FLAT_Z 4096

typedef short bf16x8 __attribute__((ext_vector_type(8)));
typedef float f32x4 __attribute__((ext_vector_type(4)));

__device__ __forceinline__ float silu_f(float x){ return x / (1.0f + expf(-x)); }

__device__ __forceinline__ void gl_lds16(const void* g, void* l){
  __builtin_amdgcn_global_load_lds(
      (const __attribute__((address_space(1))) void*)g,
      (__attribute__((address_space(3))) void*)l, 16, 0, 0);
}

// ---- fused conv_in(1x1)+silu + LN stats(fp64) + LN apply + bf16
// block=(b,half): h[b][half*64..+64][256p] in regs -> Ahi[ws*64+b][16384] bf16
__global__ __launch_bounds__(256) void k_fused_in(const float* __restrict__ x,
    const float* __restrict__ w1, const float* __restrict__ b1,
    const float* __restrict__ gp, const float* __restrict__ bp,
    const float* __restrict__ gn, const float* __restrict__ bnl,
    __hip_bfloat16* __restrict__ Ahi)
{
  int b = blockIdx.x, ws = blockIdx.y;
  int t = threadIdx.x;            // = spatial p
  int d0 = ws*64;
  float acc[64];
  #pragma unroll
  for (int j=0;j<64;j++) acc[j] = b1[d0+j];
  const float* xb = x + (size_t)b*IN_CH*SP + t;
  for (int c=0;c<IN_CH;c++){
    float xv = xb[(size_t)c*SP];
    #pragma unroll
    for (int j=0;j<64;j++) acc[j] = fmaf(xv, w1[c*CH + d0 + j], acc[j]);
  }
  double s1=0.0, s2=0.0;
  #pragma unroll
  for (int j=0;j<64;j++){
    float v = silu_f(acc[j]);
    acc[j] = v;
    double dv = (double)v;
    s1 += dv; s2 += dv*dv;
  }
  __shared__ double l1[256], l2[256];
  l1[t]=s1; l2[t]=s2; __syncthreads();
  for (int s=128; s>0; s>>=1){
    if (t<s){ l1[t]+=l1[t+s]; l2[t]+=l2[t+s]; }
    __syncthreads();
  }
  double m = l1[0]/(double)FLAT_IN;
  double v = l2[0]/(double)FLAT_IN - m*m;
  float mf = (float)m;
  float rs = (float)(1.0/sqrt(v+1e-5));
  const float* g  = ws? gn : gp;
  const float* bb = ws? bnl: bp;
  __hip_bfloat16* oh = Ahi + ((size_t)ws*64 + b)*FLAT_IN;
  #pragma unroll 4
  for (int j=0;j<64;j++){
    int k = j*256 + t;
    float val = fmaf((acc[j]-mf)*rs, g[k], bb[k]);
    oh[k] = __float2bfloat16(val);
  }
}

// ---- streaming bf16 MFMA split-K GEMM, M=64, depth-3 pipeline (4 LDS buffers).
// Block-level staging, 5 gl_lds per stage (4 W + 1 A).
// Per step: vmcnt(10) [stage k done, k+1/k+2 in flight] -> s_barrier -> STAGE(k+3) -> compute k.
// part[(wsel*KC+kc)*64 + m][N]
template<int N, int K>
__global__ __launch_bounds__(256) void k_gemm_mfma(
    const __hip_bfloat16* __restrict__ A,
    const float* __restrict__ W0, const float* __restrict__ W1,
    float* __restrict__ part, int CHUNK, int KC)
{
  __shared__ float wlds[4*4096];   // 4 x (32k x 128n) fp32 = 64KB
  __shared__ float alds[4*1024];   // 4 x (64m x 32k) bf16 = 16KB
  int nt = blockIdx.x, kc = blockIdx.y, wsel = blockIdx.z;
  const float* W = wsel ? W1 : W0;
  int t = threadIdx.x;
  int wave = t >> 6, lane = t & 63;
  int rl = lane & 15;
  int g  = lane >> 4;              // 0..3 (k-group)
  int kg = g * 8;
  int nbase = nt*128;
  int k0 = kc*CHUNK;

  const __hip_bfloat16* Aw = A + (size_t)wsel*64*K;

  // W LDS swizzle: s(kl) = ((kl>>3)&1)<<4 | ((kl>>3)&2)<<1
  int s_lane = ((g&1)<<4) | ((g&2)<<1);
  int wbase0 = kg*128 + ((wave*32 + rl) ^ s_lane);
  int wbase1 = kg*128 + ((wave*32 + 16 + rl) ^ s_lane);
  // A read byte offset within buffer: row m=mf*16+rl (64B), col16 = g ^ ((rl>>1)&3)
  int abyte[4];
  #pragma unroll
  for (int mf=0; mf<4; ++mf)
    abyte[mf] = (mf*16+rl)*64 + ((g ^ ((rl>>1)&3))<<4);

  // W stage: dest linear, source col pre-swizzled
  int src_off[4]; int dst_base[4];
  #pragma unroll
  for (int i=0;i<4;i++){
    int fi = (i*4+wave)*256 + lane*4;
    int kl = fi>>7, nn = fi&127;
    int s = (((kl>>3)&1)<<4) | (((kl>>3)&2)<<1);
    src_off[i] = kl*N + nbase + (nn ^ s);
    dst_base[i] = (i*4+wave)*256;           // wave-uniform
  }
  // A stage: thread t writes LDS bytes t*16 (m=t>>2, granule t&3); source k-quad swizzled
  size_t a_src = (size_t)(t>>2)*K + (size_t)(((t&3)^((t>>3)&3))*8);
  int a_dst = wave*256;                     // floats, wave-uniform

  f32x4 acc[4][2];
  #pragma unroll
  for (int mf=0; mf<4; ++mf){ acc[mf][0] = (f32x4){0,0,0,0}; acc[mf][1] = (f32x4){0,0,0,0}; }

  auto STAGE = [&](int buf, int ks){
    const float* Wr = W + (size_t)(k0 + ks*32)*N;
    float* lb = &wlds[buf*4096];
    #pragma unroll
    for (int i=0;i<4;i++) gl_lds16(Wr + src_off[i], lb + dst_base[i]);
    gl_lds16(Aw + a_src + (size_t)(k0 + ks*32), &alds[buf*1024] + a_dst);
  };

  int NT_ = CHUNK/32;              // >= 64
  STAGE(0, 0);
  STAGE(1, 1);
  STAGE(2, 2);

  for (int ks=0; ks<NT_; ++ks){
    int cur = ks & 3;
    __builtin_amdgcn_sched_barrier(0);
    if (ks < NT_-2)       { asm volatile("s_waitcnt vmcnt(10)" ::: "memory"); }
    else if (ks == NT_-2) { asm volatile("s_waitcnt vmcnt(5)"  ::: "memory"); }
    else                  { asm volatile("s_waitcnt vmcnt(0)"  ::: "memory"); }
    __builtin_amdgcn_sched_barrier(0);
    __builtin_amdgcn_s_barrier();            // all waves: stage ks ready, compute ks-1 done
    __builtin_amdgcn_sched_barrier(0);
    if (ks+3 < NT_) STAGE((ks+3)&3, ks+3);   // overwrites buf (ks-1)&3: consumed by all waves
    __builtin_amdgcn_sched_barrier(0);

    const float* lb = &wlds[cur*4096];
    const char* ab = (const char*)&alds[cur*1024];
    bf16x8 ah[4];
    #pragma unroll
    for (int mf=0; mf<4; ++mf) ah[mf] = *(const bf16x8*)(ab + abyte[mf]);
    float wv0[8], wv1[8];
    #pragma unroll
    for (int j=0;j<8;j++){ wv0[j] = lb[wbase0 + j*128]; wv1[j] = lb[wbase1 + j*128]; }
    bf16x8 bh0, bh1;
    #pragma unroll
    for (int j=0;j<8;j++){
      bh0[j] = __builtin_bit_cast(short, __float2bfloat16(wv0[j]));
      bh1[j] = __builtin_bit_cast(short, __float2bfloat16(wv1[j]));
    }
    #pragma unroll
    for (int mf=0; mf<4; ++mf){
      acc[mf][0] = __builtin_amdgcn_mfma_f32_16x16x32_bf16(ah[mf], bh0, acc[mf][0], 0,0,0);
      acc[mf][1] = __builtin_amdgcn_mfma_f32_16x16x32_bf16(ah[mf], bh1, acc[mf][1], 0,0,0);
    }
  }

  float* P = part + ((size_t)((wsel*KC + kc)*64))*N + nbase + wave*32 + rl;
  #pragma unroll
  for (int mf=0; mf<4; ++mf)
    #pragma unroll
    for (int f=0; f<2; ++f)
      #pragma unroll
      for (int r=0; r<4; ++r)
        P[((size_t)(mf*16 + g*4 + r))*N + f*16] = acc[mf][f][r];
}

// ---- z = sum partials + bias; z[ws][m][4096]
__global__ __launch_bounds__(256) void k_zreduce(const float* __restrict__ part,
  const float* __restrict__ bp, const float* __restrict__ bn,
  float* __restrict__ z, int KC)
{
  int idx = blockIdx.x*256 + threadIdx.x;     // < 2*64*4096
  int ws = idx >> 18; int rem = idx & 262143;
  int m = rem >> 12; int n = rem & 4095;
  float s = (ws? bn: bp)[n];
  const float* p = part + ((size_t)ws*KC*64 + m)*4096 + n;
  for (int kc=0;kc<KC;kc++) s += p[(size_t)kc*64*4096];
  z[idx] = s;
}

// ---- argmin scan over a 64-code split (cc computed per-block into LDS)
__global__ __launch_bounds__(256) void k_qscan(const float* __restrict__ z,
  const float* __restrict__ cb,
  float* __restrict__ bests, int* __restrict__ bestj)
{
  int cs = blockIdx.y;                    // 16 splits of 64 codes
  int j0 = cs*64;
  __shared__ float cc_l[64];
  if (threadIdx.x < 64){
    const float* c = cb + (size_t)(j0+threadIdx.x)*EMBED;
    float s=0.f;
    #pragma unroll
    for (int e=0;e<EMBED;e++){ float cv=c[e]; s = fmaf(cv,cv,s); }
    cc_l[threadIdx.x]=s;
  }
  __syncthreads();
  int r = blockIdx.x*256 + threadIdx.x;   // < 8192
  int ws = r>>12, rem = r&4095; int b = rem>>6, rr = rem&63;
  const float* zr = z + (size_t)ws*BB*FLAT_Z + (size_t)b*FLAT_Z + rr;
  float zr_[EMBED];
  #pragma unroll
  for (int e=0;e<EMBED;e++) zr_[e] = zr[(size_t)e*64];
  float best = 3.4e38f; int bj = 0;
  for (int jj=0;jj<64;jj++){
    int j = j0 + jj;
    const float* c = cb + (size_t)j*EMBED;
    float s1 = 0.f;
    #pragma unroll
    for (int e=0;e<EMBED;e++) s1 = fmaf(c[e], zr_[e], s1);
    float s = fmaf(-2.f, s1, cc_l[jj]);
    if (s < best){ best = s; bj = j; }   // strict < : first-index semantics
  }
  bests[(size_t)cs*8192 + r] = best;
  bestj[(size_t)cs*8192 + r] = bj;
}

// ---- finalize: combine splits, write zqA bf16 [ws*64+b][4096], row sse
__global__ __launch_bounds__(256) void k_qfin(const float* __restrict__ z,
  const float* __restrict__ cb, const float* __restrict__ bests, const int* __restrict__ bestj,
  __hip_bfloat16* __restrict__ zqA, float* __restrict__ row_sse)
{
  int r = blockIdx.x*256 + threadIdx.x;
  float best = 3.4e38f; int bj = 0;
  for (int cs=0;cs<16;cs++){              // ascending code ranges
    float v = bests[(size_t)cs*8192 + r];
    int j = bestj[(size_t)cs*8192 + r];
    if (v < best){ best=v; bj=j; }
  }
  int ws = r>>12, rem = r&4095; int b = rem>>6, rr = rem&63;
  const float* zr = z + (size_t)ws*BB*FLAT_Z + (size_t)b*FLAT_Z + rr;
  const float* c = cb + (size_t)bj*EMBED;
  __hip_bfloat16* zq = zqA + ((size_t)ws*64 + b)*FLAT_Z;
  float sse = 0.f;
  #pragma unroll
  for (int e=0;e<EMBED;e++){
    float cv = c[e];
    float zv = zr[(size_t)e*64];
    float d = cv - zv; sse = fmaf(d,d,sse);
    zq[(size_t)e*64 + rr] = __float2bfloat16(cv);
  }
  row_sse[r] = sse;
}

// ---- loss reduce (deterministic, fp64)
__global__ __launch_bounds__(256) void k_loss(const float* __restrict__ row_sse, float* __restrict__ out){
  __shared__ double l[256];
  double s=0.0;
  for (int i=threadIdx.x;i<8192;i+=256) s += (double)row_sse[i];
  l[threadIdx.x]=s; __syncthreads();
  for (int st=128;st>0;st>>=1){ if (threadIdx.x<st) l[threadIdx.x]+=l[threadIdx.x+st]; __syncthreads(); }
  if (threadIdx.x==0) out[(size_t)BB*OUT_CH*SP] = (float)(l[0]*1.25/262144.0);
}

// ---- hout reduce + bias -> h_[m][128][256]
__global__ __launch_bounds__(256) void k_hreduce(const float* __restrict__ part,
  const float* __restrict__ bp, const float* __restrict__ bn,
  float* __restrict__ hbuf, int KC)
{
  int idx = blockIdx.x*256 + threadIdx.x;  // < 2*64*16384
  int ws = idx >> 20; int rem = idx & 1048575;
  int m = rem >> 14; int n = rem & 16383;
  float s = (ws? bn: bp)[n];
  const float* p = part + ((size_t)ws*KC*64 + m)*16384 + n;
  for (int kc=0;kc<KC;kc++) s += p[(size_t)kc*64*16384];
  hbuf[((size_t)m*CH + ws*NPH + (n>>8))*SP + (n&255)] = s;
}

// ---- conv_out (silu on input) -> d_out; dg<4, 64 d each
__global__ __launch_bounds__(256) void k_conv_out(const float* __restrict__ hbuf,
  const float* __restrict__ w2, const float* __restrict__ b2, float* __restrict__ out)
{
  int b = blockIdx.x, dg = blockIdx.y;
  int p = threadIdx.x;
  int d0 = dg*64;
  float acc[64];
  #pragma unroll
  for (int j=0;j<64;j++) acc[j]=b2[d0+j];
  const float* hb = hbuf + (size_t)b*CH*SP + p;
  for (int c=0;c<CH;c++){
    float hv = silu_f(hb[(size_t)c*SP]);
    #pragma unroll
    for (int j=0;j<64;j++) acc[j] = fmaf(hv, w2[c*OUT_CH + d0 + j], acc[j]);
  }
  float* ob = out + (size_t)b*OUT_CH*SP + (size_t)d0*SP + p;
  #pragma unroll
  for (int j=0;j<64;j++) ob[(size_t)j*SP] = acc[j];
}

extern "C" void kernel_launch(void* const* d_in, const int* in_sizes, int n_in,
                              void* d_out, int out_size, void* d_ws, size_t ws_size,
                              hipStream_t stream)
{
  const float* x   = (const float*)d_in[0];
  const float* w1  = (const float*)d_in[1];
  const float* b1  = (const float*)d_in[2];
  const float* gp  = (const float*)d_in[3];
  const float* bp  = (const float*)d_in[4];
  const float* Wip = (const float*)d_in[5];
  const float* bip = (const float*)d_in[6];
  const float* gn  = (const float*)d_in[7];
  const float* bnl = (const float*)d_in[8];
  const float* Win = (const float*)d_in[9];
  const float* bin = (const float*)d_in[10];
  const float* cb  = (const float*)d_in[11];
  const float* Wop = (const float*)d_in[12];
  const float* bop = (const float*)d_in[13];
  const float* Won = (const float*)d_in[14];
  const float* bon = (const float*)d_in[15];
  const float* w2  = (const float*)d_in[16];
  const float* b2  = (const float*)d_in[17];
  float* out = (float*)d_out;
  float* ws  = (float*)d_ws;

  __hip_bfloat16* Ahi = (__hip_bfloat16*)ws;               // 1,048,576 f
  float* z    = ws + 1048576;                              // 524,288 f
  __hip_bfloat16* zqA = (__hip_bfloat16*)(ws + 1572864);   // 262,144 f
  float* hh   = ws + 1835008;                              // 2,097,152 f
  float* sse  = ws + 3933184;                              // 8,192 f
  float* bests= ws + 3941376;                              // 131,072 f
  int*   bestj= (int*)(ws + 4072448);                      // 131,072
  float* part = ws + 4203520;                              // 4,194,304 f

  size_t wsf = ws_size/4;
  int KCe=8, KCd=2;                                        // 512-block grids (2 blocks/CU)
  if (wsf < (size_t)4203520 + 4194304) { KCe=4; KCd=1; }

  k_fused_in<<<dim3(64,2),256,0,stream>>>(x,w1,b1,gp,bp,gn,bnl,Ahi);
  k_gemm_mfma<4096,16384><<<dim3(32,KCe,2),256,0,stream>>>(Ahi,Wip,Win,part,16384/KCe,KCe);
  k_zreduce<<<2048,256,0,stream>>>(part,bip,bin,z,KCe);
  k_qscan<<<dim3(32,16),256,0,stream>>>(z,cb,bests,bestj);
  k_qfin<<<32,256,0,stream>>>(z,cb,bests,bestj,zqA,sse);
  k_gemm_mfma<16384,4096><<<dim3(128,KCd,2),256,0,stream>>>(zqA,Wop,Won,part,4096/KCd,KCd);
  k_hreduce<<<8192,256,0,stream>>>(part,bop,bon,hh,KCd);
  k_conv_out<<<dim3(64,4),256,0,stream>>>(hh,w2,b2,out);
  k_loss<<<1,256,0,stream>>>(sse,out);
}